// Round 1
// baseline (1864.445 us; speedup 1.0000x reference)
//
#include <hip/hip_runtime.h>

#define H96 96

// ---------------- degree / norm ----------------
__global__ void deg_kernel(const int* __restrict__ src, const int* __restrict__ dst,
                           float* __restrict__ dout, float* __restrict__ din, int E) {
    int e = blockIdx.x * blockDim.x + threadIdx.x;
    if (e < E) {
        atomicAdd(dout + src[e], 1.0f);
        atomicAdd(din + dst[e], 1.0f);
    }
}

__global__ void norm_kernel(float* __restrict__ no, float* __restrict__ ni, int N) {
    int i = blockIdx.x * blockDim.x + threadIdx.x;
    if (i < N) {
        no[i] = rsqrtf(fmaxf(no[i], 1.0f));
        ni[i] = rsqrtf(fmaxf(ni[i], 1.0f));
    }
}

// wsum[c] = sum_j Wm[c,j]  (row sums), bsum = sum(bm)
__global__ void wsum_kernel(const float* __restrict__ Wm, const float* __restrict__ bm,
                            float* __restrict__ wsum, float* __restrict__ bsum) {
    int c = threadIdx.x;
    if (c < H96) {
        float s = 0.f;
        for (int j = 0; j < H96; j++) s += Wm[c * H96 + j];
        wsum[c] = s;
    }
    if (c == 0) {
        float s = 0.f;
        for (int j = 0; j < H96; j++) s += bm[j];
        bsum[0] = s;
    }
}

// ---------------- fp32 tiled GEMM: C[M,96] = A[M,K] @ B[K,96] ----------------
#define BM 64
#define BK 32
__global__ __launch_bounds__(256) void gemm_kernel(const float* __restrict__ A,
                                                   const float* __restrict__ B,
                                                   float* __restrict__ C, int M, int K) {
    __shared__ float As[BM * (BK + 1)];   // 64 x 33
    __shared__ float Bs[BK * H96];        // 32 x 96
    int tid = threadIdx.x;
    int tx = tid & 15, ty = tid >> 4;     // 16 x 16 thread grid
    int row0 = blockIdx.x * BM;
    int r0 = ty * 4, c0 = tx * 6;         // 4 rows x 6 cols per thread
    float acc[4][6] = {};

    for (int k0 = 0; k0 < K; k0 += BK) {
        // A tile: 64x32 = 2048 elems, 8 per thread, coalesced along K
#pragma unroll
        for (int i = 0; i < 8; i++) {
            int idx = tid + i * 256;
            int r = idx >> 5, kk = idx & 31;
            int gr = row0 + r, gk = k0 + kk;
            As[r * (BK + 1) + kk] = (gr < M && gk < K) ? A[(size_t)gr * K + gk] : 0.f;
        }
        // B tile: 32x96 = 3072 elems, 12 per thread, coalesced along cols
#pragma unroll
        for (int i = 0; i < 12; i++) {
            int idx = tid + i * 256;
            int kk = idx / H96, c = idx - kk * H96;
            int gk = k0 + kk;
            Bs[kk * H96 + c] = (gk < K) ? B[gk * H96 + c] : 0.f;
        }
        __syncthreads();
#pragma unroll
        for (int kk = 0; kk < BK; kk++) {
            float a[4], b[6];
#pragma unroll
            for (int i = 0; i < 4; i++) a[i] = As[(r0 + i) * (BK + 1) + kk];
#pragma unroll
            for (int j = 0; j < 6; j++) b[j] = Bs[kk * H96 + c0 + j];
#pragma unroll
            for (int i = 0; i < 4; i++)
#pragma unroll
                for (int j = 0; j < 6; j++)
                    acc[i][j] = fmaf(a[i], b[j], acc[i][j]);
        }
        __syncthreads();
    }
#pragma unroll
    for (int i = 0; i < 4; i++) {
        int gr = row0 + r0 + i;
        if (gr < M) {
#pragma unroll
            for (int j = 0; j < 6; j++)
                C[(size_t)gr * H96 + c0 + j] = acc[i][j];
        }
    }
}

// ---------------- SpMM: out[dst] += scale(src) * feat[rowmap(src)] ----------------
// blockDim = (96, 4): threadIdx.x = channel, threadIdx.y = edge within block
__global__ __launch_bounds__(384) void spmm_kernel(const float* __restrict__ feat,
                                                   const int* __restrict__ src,
                                                   const int* __restrict__ dst,
                                                   const int* __restrict__ perm,
                                                   const float* __restrict__ norm,
                                                   float* __restrict__ out, int E) {
    int e = blockIdx.x * 4 + threadIdx.y;
    if (e >= E) return;
    int s = src[e];
    int d = dst[e];
    int row = perm ? perm[s] : s;
    float scale = norm ? norm[s] : 1.0f;
    int c = threadIdx.x;
    float v = scale * feat[(size_t)row * H96 + c];
    atomicAdd(out + (size_t)d * H96 + c, v);
}

// ---------------- layer-1 epilogue: h1s = prelu(agg*norm_in + b1) * norm_out ----------------
__global__ void act1_kernel(const float* __restrict__ agg, const float* __restrict__ norm_in,
                            const float* __restrict__ norm_out, const float* __restrict__ b,
                            const float* __restrict__ a, float* __restrict__ outp, int N) {
    int i = blockIdx.x * blockDim.x + threadIdx.x;
    int total = N * H96;
    if (i < total) {
        int node = i / H96;
        int c = i - node * H96;
        float h = agg[i] * norm_in[node] + b[c];
        h = (h >= 0.f) ? h : a[c] * h;
        outp[i] = h * norm_out[node];
    }
}

// ---------------- final: out[i] = dot(prelu(agg*norm_in + b2), wsum) + bsum ----------------
__global__ void final_kernel(const float* __restrict__ agg, const float* __restrict__ norm_in,
                             const float* __restrict__ b2, const float* __restrict__ a2,
                             const float* __restrict__ wsum, const float* __restrict__ bsum,
                             float* __restrict__ outp, int N) {
    int i = blockIdx.x * blockDim.x + threadIdx.x;
    if (i < N) {
        float ni = norm_in[i];
        float s = 0.f;
        const float* row = agg + (size_t)i * H96;
#pragma unroll 8
        for (int c = 0; c < H96; c++) {
            float h = row[c] * ni + b2[c];
            h = (h >= 0.f) ? h : a2[c] * h;
            s += h * wsum[c];
        }
        outp[i] = s + bsum[0];
    }
}

extern "C" void kernel_launch(void* const* d_in, const int* in_sizes, int n_in,
                              void* d_out, int out_size, void* d_ws, size_t ws_size,
                              hipStream_t stream) {
    const float* x    = (const float*)d_in[0];
    const int*   src  = (const int*)d_in[1];
    const int*   dst  = (const int*)d_in[2];
    const int*   perm = (const int*)d_in[3];
    const float* W1   = (const float*)d_in[4];
    const float* b1   = (const float*)d_in[5];
    const float* a1   = (const float*)d_in[6];
    const float* W2   = (const float*)d_in[7];
    const float* b2   = (const float*)d_in[8];
    const float* a2   = (const float*)d_in[9];
    const float* Wm   = (const float*)d_in[10];
    const float* bm   = (const float*)d_in[11];
    float* out = (float*)d_out;

    int E = in_sizes[1];
    int N = in_sizes[3];
    int F = in_sizes[0] / N;

    float* ws = (float*)d_ws;
    float* norm_out = ws;                      // N
    float* norm_in  = ws + N;                  // N
    float* wsum     = ws + 2 * N;              // 128 (96 used)
    float* bsum     = ws + 2 * N + 128;        // 1 (padded)
    float* bufA     = ws + 2 * N + 256;        // N*96  (y = x@W1, shared by views)
    float* bufB     = bufA + (size_t)N * H96;  // N*96
    float* bufC     = bufB + (size_t)N * H96;  // N*96

    hipMemsetAsync(norm_out, 0, (size_t)N * sizeof(float), stream);
    hipMemsetAsync(norm_in, 0, (size_t)N * sizeof(float), stream);
    deg_kernel<<<(E + 255) / 256, 256, 0, stream>>>(src, dst, norm_out, norm_in, E);
    norm_kernel<<<(N + 255) / 256, 256, 0, stream>>>(norm_out, norm_in, N);
    wsum_kernel<<<1, 128, 0, stream>>>(Wm, bm, wsum, bsum);

    // y = x @ W1 (shared across both views)
    gemm_kernel<<<(N + BM - 1) / BM, 256, 0, stream>>>(x, W1, bufA, N, F);

    for (int v = 0; v < 2; v++) {
        const int* p = v ? perm : nullptr;
        // layer 1 SpMM: bufB[dst] += norm_out[src] * y[perm?[src]]
        hipMemsetAsync(bufB, 0, (size_t)N * H96 * sizeof(float), stream);
        spmm_kernel<<<(E + 3) / 4, dim3(H96, 4), 0, stream>>>(bufA, src, dst, p, norm_out, bufB, E);
        // h1s = prelu(bufB*norm_in + b1; a1) * norm_out   (norm_out of layer-2 folded in)
        act1_kernel<<<((size_t)N * H96 + 255) / 256, 256, 0, stream>>>(bufB, norm_in, norm_out, b1, a1, bufC, N);
        // t = h1s @ W2
        gemm_kernel<<<(N + BM - 1) / BM, 256, 0, stream>>>(bufC, W2, bufB, N, H96);
        // layer 2 SpMM: bufC[dst] += t[src]
        hipMemsetAsync(bufC, 0, (size_t)N * H96 * sizeof(float), stream);
        spmm_kernel<<<(E + 3) / 4, dim3(H96, 4), 0, stream>>>(bufB, src, dst, nullptr, nullptr, bufC, E);
        // out[i] = dot(prelu(bufC*norm_in + b2; a2), wsum) + bsum
        final_kernel<<<(N + 255) / 256, 256, 0, stream>>>(bufC, norm_in, b2, a2, wsum, bsum,
                                                          out + (size_t)v * N, N);
    }
}

// Round 2
// 995.797 us; speedup vs baseline: 1.8723x; 1.8723x over previous
//
#include <hip/hip_runtime.h>

#define H96 96
#define BM 128
#define BK 32
#define BKP 33   // +1 pad: A-tile reads spread banks

// ---------------- degrees (int) ----------------
__global__ void deg_kernel(const int* __restrict__ src, const int* __restrict__ dst,
                           int* __restrict__ dout, int* __restrict__ din, int E) {
    int e = blockIdx.x * blockDim.x + threadIdx.x;
    if (e < E) {
        atomicAdd(dout + src[e], 1);
        atomicAdd(din + dst[e], 1);
    }
}

__global__ void norm_kernel(const int* __restrict__ dO, const int* __restrict__ dI,
                            float* __restrict__ no, float* __restrict__ ni, int N) {
    int i = blockIdx.x * blockDim.x + threadIdx.x;
    if (i < N) {
        no[i] = rsqrtf(fmaxf((float)dO[i], 1.0f));
        ni[i] = rsqrtf(fmaxf((float)dI[i], 1.0f));
    }
}

// ---------------- scan (exclusive) over deg_in -> row_start, cursor ----------------
__global__ void scan1_kernel(const int* __restrict__ deg, int* __restrict__ pre,
                             int* __restrict__ bsums, int N) {
    __shared__ int s[256];
    int i = blockIdx.x * 256 + threadIdx.x;
    int v = (i < N) ? deg[i] : 0;
    s[threadIdx.x] = v;
    __syncthreads();
    for (int off = 1; off < 256; off <<= 1) {
        int t = (threadIdx.x >= off) ? s[threadIdx.x - off] : 0;
        __syncthreads();
        s[threadIdx.x] += t;
        __syncthreads();
    }
    if (i < N) pre[i] = s[threadIdx.x] - v;  // exclusive
    if (threadIdx.x == 255) bsums[blockIdx.x] = s[255];
}

__global__ void scan2_kernel(int* __restrict__ bsums, int nb) {
    __shared__ int s[256];
    int v = (threadIdx.x < nb) ? bsums[threadIdx.x] : 0;
    s[threadIdx.x] = v;
    __syncthreads();
    for (int off = 1; off < 256; off <<= 1) {
        int t = (threadIdx.x >= off) ? s[threadIdx.x - off] : 0;
        __syncthreads();
        s[threadIdx.x] += t;
        __syncthreads();
    }
    if (threadIdx.x < nb) bsums[threadIdx.x] = s[threadIdx.x] - v;  // exclusive
}

__global__ void scan3_kernel(const int* __restrict__ pre, const int* __restrict__ bsums,
                             int* __restrict__ row_start, int* __restrict__ cursor,
                             int N, int E) {
    int i = blockIdx.x * 256 + threadIdx.x;
    if (i < N) {
        int v = pre[i] + bsums[blockIdx.x];
        row_start[i] = v;
        cursor[i] = v;
    }
    if (i == 0) row_start[N] = E;
}

__global__ void scatter_kernel(const int* __restrict__ src, const int* __restrict__ dst,
                               int* __restrict__ cursor, int* __restrict__ csr_src, int E) {
    int e = blockIdx.x * 256 + threadIdx.x;
    if (e < E) {
        int d = dst[e];
        int p = atomicAdd(cursor + d, 1);
        csr_src[p] = src[e];
    }
}

// wsum[c] = sum_j Wm[c,j]  (row sums), bsum = sum(bm)
__global__ void wsum_kernel(const float* __restrict__ Wm, const float* __restrict__ bm,
                            float* __restrict__ wsum, float* __restrict__ bsum) {
    int c = threadIdx.x;
    if (c < H96) {
        float s = 0.f;
        for (int j = 0; j < H96; j++) s += Wm[c * H96 + j];
        wsum[c] = s;
    }
    if (c == 0) {
        float s = 0.f;
        for (int j = 0; j < H96; j++) s += bm[j];
        bsum[0] = s;
    }
}

// ---------------- fp32 GEMM: C[M,96] = A[M,K] @ B[K,96], reg-prefetch pipeline ----------------
__global__ __launch_bounds__(256) void gemm_kernel(const float* __restrict__ A,
                                                   const float* __restrict__ B,
                                                   float* __restrict__ C, int M, int K) {
    __shared__ float As[BM * BKP];   // 128 x 33 = 16.9 KB
    __shared__ float Bs[BK * H96];   // 32 x 96  = 12 KB
    int tid = threadIdx.x;
    int tx = tid & 7;                // 8 col groups of 12
    int ty = tid >> 3;               // 32 row groups of 4
    int row0 = blockIdx.x * BM;
    int r0 = ty * 4, c0 = tx * 12;
    alignas(16) float acc[4][12] = {};
    float4 pa[4], pb[3];

    int nk = (K + BK - 1) / BK;

    // stage tile 0 into regs
#pragma unroll
    for (int i = 0; i < 4; i++) {
        int idx = tid + i * 256;
        int r = idx >> 3, kq = idx & 7;
        int gr = row0 + r, gk = kq * 4;
        pa[i] = (gr < M && gk < K) ? *(const float4*)(A + (size_t)gr * K + gk)
                                   : make_float4(0.f, 0.f, 0.f, 0.f);
    }
#pragma unroll
    for (int i = 0; i < 3; i++) {
        int idx = tid + i * 256;
        int kk = idx / 24, cq = idx - kk * 24;
        pb[i] = (kk < K) ? *(const float4*)(B + (size_t)kk * H96 + cq * 4)
                         : make_float4(0.f, 0.f, 0.f, 0.f);
    }

    for (int t = 0; t < nk; t++) {
        // write staged regs to LDS
#pragma unroll
        for (int i = 0; i < 4; i++) {
            int idx = tid + i * 256;
            int r = idx >> 3, kq = idx & 7;
            As[r * BKP + kq * 4 + 0] = pa[i].x;
            As[r * BKP + kq * 4 + 1] = pa[i].y;
            As[r * BKP + kq * 4 + 2] = pa[i].z;
            As[r * BKP + kq * 4 + 3] = pa[i].w;
        }
#pragma unroll
        for (int i = 0; i < 3; i++) {
            int idx = tid + i * 256;
            int kk = idx / 24, cq = idx - kk * 24;
            *(float4*)(&Bs[kk * H96 + cq * 4]) = pb[i];
        }
        __syncthreads();

        // prefetch next tile while computing this one
        if (t + 1 < nk) {
            int k0 = (t + 1) * BK;
#pragma unroll
            for (int i = 0; i < 4; i++) {
                int idx = tid + i * 256;
                int r = idx >> 3, kq = idx & 7;
                int gr = row0 + r, gk = k0 + kq * 4;
                pa[i] = (gr < M && gk < K) ? *(const float4*)(A + (size_t)gr * K + gk)
                                           : make_float4(0.f, 0.f, 0.f, 0.f);
            }
#pragma unroll
            for (int i = 0; i < 3; i++) {
                int idx = tid + i * 256;
                int kk = idx / 24, cq = idx - kk * 24;
                int gk = k0 + kk;
                pb[i] = (gk < K) ? *(const float4*)(B + (size_t)gk * H96 + cq * 4)
                                 : make_float4(0.f, 0.f, 0.f, 0.f);
            }
        }

#pragma unroll 8
        for (int k = 0; k < BK; k++) {
            float a[4];
            alignas(16) float b[12];
#pragma unroll
            for (int i = 0; i < 4; i++) a[i] = As[(r0 + i) * BKP + k];
#pragma unroll
            for (int j = 0; j < 3; j++)
                *(float4*)&b[j * 4] = *(const float4*)&Bs[k * H96 + c0 + j * 4];
#pragma unroll
            for (int i = 0; i < 4; i++)
#pragma unroll
                for (int j = 0; j < 12; j++)
                    acc[i][j] = fmaf(a[i], b[j], acc[i][j]);
        }
        __syncthreads();
    }

#pragma unroll
    for (int i = 0; i < 4; i++) {
        int gr = row0 + r0 + i;
        if (gr < M) {
#pragma unroll
            for (int j = 0; j < 3; j++)
                *(float4*)(C + (size_t)gr * H96 + c0 + j * 4) = *(const float4*)&acc[i][j * 4];
        }
    }
}

// ---------------- CSR SpMM with fused epilogues ----------------
// blockDim = (96, 4). mode 1: write h1s = prelu(agg*ni + b; a) * no
// mode 2: out[d] = dot(prelu(agg*ni + b; a), wsum) + bsum
__global__ __launch_bounds__(384) void spmm_csr_kernel(
        const float* __restrict__ feat, const int* __restrict__ row_start,
        const int* __restrict__ csr_src,
        const int* __restrict__ perm,        // nullable
        const float* __restrict__ scale_arr, // nullable
        const float* __restrict__ norm_in, const float* __restrict__ norm_out_mul,
        const float* __restrict__ b, const float* __restrict__ a,
        const float* __restrict__ wsum, const float* __restrict__ bsum,
        float* __restrict__ outp, int N, int mode) {
    int d = blockIdx.x * 4 + threadIdx.y;
    int c = threadIdx.x;
    __shared__ float red[4][H96];
    float acc = 0.f;
    if (d < N) {
        int beg = row_start[d], end = row_start[d + 1];
        for (int j = beg; j < end; j++) {
            int s = csr_src[j];
            float sc = scale_arr ? scale_arr[s] : 1.0f;
            int row = perm ? perm[s] : s;
            acc = fmaf(sc, feat[(size_t)row * H96 + c], acc);
        }
    }
    if (mode == 1) {
        if (d < N) {
            float h = fmaf(acc, norm_in[d], b[c]);
            h = (h >= 0.f) ? h : a[c] * h;
            outp[(size_t)d * H96 + c] = h * norm_out_mul[d];
        }
    } else {
        float h = (d < N) ? fmaf(acc, norm_in[d], b[c]) : 0.f;
        h = (h >= 0.f) ? h : a[c] * h;
        red[threadIdx.y][c] = h * wsum[c];
        __syncthreads();
        if (c < 32) {
            float s2 = red[threadIdx.y][c] + red[threadIdx.y][c + 32] + red[threadIdx.y][c + 64];
#pragma unroll
            for (int off = 16; off > 0; off >>= 1) s2 += __shfl_down(s2, off, 32);
            if (c == 0 && d < N) outp[d] = s2 + bsum[0];
        }
    }
}

extern "C" void kernel_launch(void* const* d_in, const int* in_sizes, int n_in,
                              void* d_out, int out_size, void* d_ws, size_t ws_size,
                              hipStream_t stream) {
    const float* x    = (const float*)d_in[0];
    const int*   src  = (const int*)d_in[1];
    const int*   dst  = (const int*)d_in[2];
    const int*   perm = (const int*)d_in[3];
    const float* W1   = (const float*)d_in[4];
    const float* b1   = (const float*)d_in[5];
    const float* a1   = (const float*)d_in[6];
    const float* W2   = (const float*)d_in[7];
    const float* b2   = (const float*)d_in[8];
    const float* a2   = (const float*)d_in[9];
    const float* Wm   = (const float*)d_in[10];
    const float* bm   = (const float*)d_in[11];
    float* out = (float*)d_out;

    int E = in_sizes[1];
    int N = in_sizes[3];
    int F = in_sizes[0] / N;

    size_t NP = ((size_t)N + 255) & ~(size_t)255;
    size_t EP = ((size_t)E + 255) & ~(size_t)255;
    int* deg_out   = (int*)d_ws;          // NP
    int* deg_in    = deg_out + NP;        // NP
    int* pre       = deg_in + NP;         // NP (scratch exclusive-scan partial)
    int* row_start = pre + NP;            // NP (N+1 used)
    int* cursor    = row_start + NP;      // NP
    int* bsums     = cursor + NP;         // 256
    int* csr_src   = bsums + 256;         // EP
    float* norm_out = (float*)(csr_src + EP);  // NP
    float* norm_in  = norm_out + NP;           // NP
    float* wsum     = norm_in + NP;            // 256
    float* bsum     = wsum + 256;              // 256
    float* y        = bsum + 256;              // N*96
    float* h1s      = y + (size_t)N * H96;     // N*96
    float* tbuf     = h1s + (size_t)N * H96;   // N*96

    hipMemsetAsync(deg_out, 0, 2 * NP * sizeof(int), stream);
    deg_kernel<<<(E + 255) / 256, 256, 0, stream>>>(src, dst, deg_out, deg_in, E);
    norm_kernel<<<(N + 255) / 256, 256, 0, stream>>>(deg_out, deg_in, norm_out, norm_in, N);

    int nb = (N + 255) / 256;
    scan1_kernel<<<nb, 256, 0, stream>>>(deg_in, pre, bsums, N);
    scan2_kernel<<<1, 256, 0, stream>>>(bsums, nb);
    scan3_kernel<<<nb, 256, 0, stream>>>(pre, bsums, row_start, cursor, N, E);
    scatter_kernel<<<(E + 255) / 256, 256, 0, stream>>>(src, dst, cursor, csr_src, E);
    wsum_kernel<<<1, 128, 0, stream>>>(Wm, bm, wsum, bsum);

    // y = x @ W1 (shared across both views)
    gemm_kernel<<<(N + BM - 1) / BM, 256, 0, stream>>>(x, W1, y, N, F);

    for (int v = 0; v < 2; v++) {
        const int* p = v ? perm : nullptr;
        // layer 1: agg[d] = sum norm_out[s] * y[perm?[s]]; fused act1 (+norm_out fold)
        spmm_csr_kernel<<<(N + 3) / 4, dim3(H96, 4), 0, stream>>>(
            y, row_start, csr_src, p, norm_out, norm_in, norm_out, b1, a1,
            nullptr, nullptr, h1s, N, 1);
        // t = h1s @ W2
        gemm_kernel<<<(N + BM - 1) / BM, 256, 0, stream>>>(h1s, W2, tbuf, N, H96);
        // layer 2: agg[d] = sum t[s]; fused prelu + dot(wsum) + bsum
        spmm_csr_kernel<<<(N + 3) / 4, dim3(H96, 4), 0, stream>>>(
            tbuf, row_start, csr_src, nullptr, nullptr, norm_in, nullptr, b2, a2,
            wsum, bsum, out + (size_t)v * N, N, 2);
    }
}

// Round 3
// 812.681 us; speedup vs baseline: 2.2942x; 1.2253x over previous
//
#include <hip/hip_runtime.h>

#define H96 96

// ---------------- degrees (int) ----------------
__global__ void deg_kernel(const int* __restrict__ src, const int* __restrict__ dst,
                           int* __restrict__ dout, int* __restrict__ din, int E) {
    int e = blockIdx.x * blockDim.x + threadIdx.x;
    if (e < E) {
        atomicAdd(dout + src[e], 1);
        atomicAdd(din + dst[e], 1);
    }
}

__global__ void norm_kernel(const int* __restrict__ dO, const int* __restrict__ dI,
                            float* __restrict__ no, float* __restrict__ ni, int N) {
    int i = blockIdx.x * blockDim.x + threadIdx.x;
    if (i < N) {
        no[i] = rsqrtf(fmaxf((float)dO[i], 1.0f));
        ni[i] = rsqrtf(fmaxf((float)dI[i], 1.0f));
    }
}

// ---------------- exclusive scan over deg_in -> row_start, cursor ----------------
__global__ void scan1_kernel(const int* __restrict__ deg, int* __restrict__ pre,
                             int* __restrict__ bsums, int N) {
    __shared__ int s[256];
    int i = blockIdx.x * 256 + threadIdx.x;
    int v = (i < N) ? deg[i] : 0;
    s[threadIdx.x] = v;
    __syncthreads();
    for (int off = 1; off < 256; off <<= 1) {
        int t = (threadIdx.x >= off) ? s[threadIdx.x - off] : 0;
        __syncthreads();
        s[threadIdx.x] += t;
        __syncthreads();
    }
    if (i < N) pre[i] = s[threadIdx.x] - v;
    if (threadIdx.x == 255) bsums[blockIdx.x] = s[255];
}

__global__ void scan2_kernel(int* __restrict__ bsums, int nb) {
    __shared__ int s[256];
    int v = (threadIdx.x < nb) ? bsums[threadIdx.x] : 0;
    s[threadIdx.x] = v;
    __syncthreads();
    for (int off = 1; off < 256; off <<= 1) {
        int t = (threadIdx.x >= off) ? s[threadIdx.x - off] : 0;
        __syncthreads();
        s[threadIdx.x] += t;
        __syncthreads();
    }
    if (threadIdx.x < nb) bsums[threadIdx.x] = s[threadIdx.x] - v;
}

__global__ void scan3_kernel(const int* __restrict__ pre, const int* __restrict__ bsums,
                             int* __restrict__ row_start, int* __restrict__ cursor,
                             int N, int E) {
    int i = blockIdx.x * 256 + threadIdx.x;
    if (i < N) {
        int v = pre[i] + bsums[blockIdx.x];
        row_start[i] = v;
        cursor[i] = v;
    }
    if (i == 0) row_start[N] = E;
}

__global__ void scatter_kernel(const int* __restrict__ src, const int* __restrict__ dst,
                               int* __restrict__ cursor, int* __restrict__ csr_src, int E) {
    int e = blockIdx.x * 256 + threadIdx.x;
    if (e < E) {
        int d = dst[e];
        int p = atomicAdd(cursor + d, 1);
        csr_src[p] = src[e];
    }
}

// ---------------- degree counting sort: order[] = nodes sorted by deg_in ----------------
__global__ void hist_kernel(const int* __restrict__ deg, int* __restrict__ hist, int N) {
    int i = blockIdx.x * 256 + threadIdx.x;
    if (i < N) atomicAdd(hist + min(deg[i], 255), 1);
}

__global__ void hist_scan_kernel(const int* __restrict__ hist, int* __restrict__ cursor) {
    __shared__ int s[256];
    int v = hist[threadIdx.x];
    s[threadIdx.x] = v;
    __syncthreads();
    for (int off = 1; off < 256; off <<= 1) {
        int t = (threadIdx.x >= off) ? s[threadIdx.x - off] : 0;
        __syncthreads();
        s[threadIdx.x] += t;
        __syncthreads();
    }
    cursor[threadIdx.x] = s[threadIdx.x] - v;
}

__global__ void order_kernel(const int* __restrict__ deg, int* __restrict__ cursor,
                             int* __restrict__ order, int N) {
    int i = blockIdx.x * 256 + threadIdx.x;
    if (i < N) {
        int p = atomicAdd(cursor + min(deg[i], 255), 1);
        order[p] = i;
    }
}

// wsum[c] = row sums of Wm, bsum = sum(bm)
__global__ void wsum_kernel(const float* __restrict__ Wm, const float* __restrict__ bm,
                            float* __restrict__ wsum, float* __restrict__ bsum) {
    int c = threadIdx.x;
    if (c < H96) {
        float s = 0.f;
        for (int j = 0; j < H96; j++) s += Wm[c * H96 + j];
        wsum[c] = s;
    }
    if (c == 0) {
        float s = 0.f;
        for (int j = 0; j < H96; j++) s += bm[j];
        bsum[0] = s;
    }
}

// ---------------- fp32 GEMM: C[M,96] = A[M,K] @ B[K,96] ----------------
#define BM 128
#define BK 32
#define BKP 33
__global__ __launch_bounds__(256) void gemm_kernel(const float* __restrict__ A,
                                                   const float* __restrict__ B,
                                                   float* __restrict__ C, int M, int K) {
    __shared__ float As[BM * BKP];
    __shared__ float Bs[BK * H96];
    int tid = threadIdx.x;
    int tx = tid & 7, ty = tid >> 3;
    int row0 = blockIdx.x * BM;
    int r0 = ty * 4, c0 = tx * 12;
    alignas(16) float acc[4][12] = {};
    float4 pa[4], pb[3];
    int nk = (K + BK - 1) / BK;

#pragma unroll
    for (int i = 0; i < 4; i++) {
        int idx = tid + i * 256;
        int r = idx >> 3, kq = idx & 7;
        int gr = row0 + r, gk = kq * 4;
        pa[i] = (gr < M && gk < K) ? *(const float4*)(A + (size_t)gr * K + gk)
                                   : make_float4(0.f, 0.f, 0.f, 0.f);
    }
#pragma unroll
    for (int i = 0; i < 3; i++) {
        int idx = tid + i * 256;
        int kk = idx / 24, cq = idx - kk * 24;
        pb[i] = (kk < K) ? *(const float4*)(B + (size_t)kk * H96 + cq * 4)
                         : make_float4(0.f, 0.f, 0.f, 0.f);
    }

    for (int t = 0; t < nk; t++) {
#pragma unroll
        for (int i = 0; i < 4; i++) {
            int idx = tid + i * 256;
            int r = idx >> 3, kq = idx & 7;
            As[r * BKP + kq * 4 + 0] = pa[i].x;
            As[r * BKP + kq * 4 + 1] = pa[i].y;
            As[r * BKP + kq * 4 + 2] = pa[i].z;
            As[r * BKP + kq * 4 + 3] = pa[i].w;
        }
#pragma unroll
        for (int i = 0; i < 3; i++) {
            int idx = tid + i * 256;
            int kk = idx / 24, cq = idx - kk * 24;
            *(float4*)(&Bs[kk * H96 + cq * 4]) = pb[i];
        }
        __syncthreads();

        if (t + 1 < nk) {
            int k0 = (t + 1) * BK;
#pragma unroll
            for (int i = 0; i < 4; i++) {
                int idx = tid + i * 256;
                int r = idx >> 3, kq = idx & 7;
                int gr = row0 + r, gk = k0 + kq * 4;
                pa[i] = (gr < M && gk < K) ? *(const float4*)(A + (size_t)gr * K + gk)
                                           : make_float4(0.f, 0.f, 0.f, 0.f);
            }
#pragma unroll
            for (int i = 0; i < 3; i++) {
                int idx = tid + i * 256;
                int kk = idx / 24, cq = idx - kk * 24;
                int gk = k0 + kk;
                pb[i] = (gk < K) ? *(const float4*)(B + (size_t)gk * H96 + cq * 4)
                                 : make_float4(0.f, 0.f, 0.f, 0.f);
            }
        }

#pragma unroll 8
        for (int k = 0; k < BK; k++) {
            float a[4];
            alignas(16) float b[12];
#pragma unroll
            for (int i = 0; i < 4; i++) a[i] = As[(r0 + i) * BKP + k];
#pragma unroll
            for (int j = 0; j < 3; j++)
                *(float4*)&b[j * 4] = *(const float4*)&Bs[k * H96 + c0 + j * 4];
#pragma unroll
            for (int i = 0; i < 4; i++)
#pragma unroll
                for (int j = 0; j < 12; j++)
                    acc[i][j] = fmaf(a[i], b[j], acc[i][j]);
        }
        __syncthreads();
    }

#pragma unroll
    for (int i = 0; i < 4; i++) {
        int gr = row0 + r0 + i;
        if (gr < M) {
#pragma unroll
            for (int j = 0; j < 3; j++)
                *(float4*)(C + (size_t)gr * H96 + c0 + j * 4) = *(const float4*)&acc[i][j * 4];
        }
    }
}

// ---------------- helpers ----------------
__device__ __forceinline__ void fma4(float4& a, float s, const float4& v) {
    a.x = fmaf(s, v.x, a.x);
    a.y = fmaf(s, v.y, a.y);
    a.z = fmaf(s, v.z, a.z);
    a.w = fmaf(s, v.w, a.w);
}

__device__ __forceinline__ float4 prelu4(float4 acc, float ni, float4 b, float4 a) {
    float4 h;
    h.x = fmaf(acc.x, ni, b.x); h.x = (h.x >= 0.f) ? h.x : a.x * h.x;
    h.y = fmaf(acc.y, ni, b.y); h.y = (h.y >= 0.f) ? h.y : a.y * h.y;
    h.z = fmaf(acc.z, ni, b.z); h.z = (h.z >= 0.f) ? h.z : a.z * h.z;
    h.w = fmaf(acc.w, ni, b.w); h.w = (h.w >= 0.f) ? h.w : a.w * h.w;
    return h;
}

// ---------------- layer-1 dual-view SpMM, float4, 4-edge unroll ----------------
// blockDim(24,16): tx = channel quad, ty = node slot. No barriers needed.
__global__ __launch_bounds__(384) void spmm1_dual(
        const float4* __restrict__ y4, const int* __restrict__ row_start,
        const int* __restrict__ csr_src, const int* __restrict__ order,
        const int* __restrict__ perm, const float* __restrict__ norm_out,
        const float* __restrict__ norm_in,
        const float* __restrict__ b1, const float* __restrict__ a1,
        float4* __restrict__ h1, float4* __restrict__ h2, int N) {
    int g = blockIdx.x * 16 + threadIdx.y;
    if (g >= N) return;
    int d = order[g];
    int tx = threadIdx.x;
    int beg = row_start[d], end = row_start[d + 1];
    const float4* yt = y4 + tx;
    float4 acc1 = make_float4(0.f, 0.f, 0.f, 0.f);
    float4 acc2 = make_float4(0.f, 0.f, 0.f, 0.f);
    int j = beg;
    for (; j + 4 <= end; j += 4) {
        int s0 = csr_src[j], s1 = csr_src[j + 1], s2 = csr_src[j + 2], s3 = csr_src[j + 3];
        float n0 = norm_out[s0], n1 = norm_out[s1], n2 = norm_out[s2], n3 = norm_out[s3];
        int p0 = perm[s0], p1 = perm[s1], p2 = perm[s2], p3 = perm[s3];
        float4 u0 = yt[(size_t)s0 * 24], u1 = yt[(size_t)s1 * 24];
        float4 u2 = yt[(size_t)s2 * 24], u3 = yt[(size_t)s3 * 24];
        float4 w0 = yt[(size_t)p0 * 24], w1 = yt[(size_t)p1 * 24];
        float4 w2 = yt[(size_t)p2 * 24], w3 = yt[(size_t)p3 * 24];
        fma4(acc1, n0, u0); fma4(acc1, n1, u1); fma4(acc1, n2, u2); fma4(acc1, n3, u3);
        fma4(acc2, n0, w0); fma4(acc2, n1, w1); fma4(acc2, n2, w2); fma4(acc2, n3, w3);
    }
    for (; j < end; j++) {
        int s = csr_src[j];
        float n = norm_out[s];
        int p = perm[s];
        fma4(acc1, n, yt[(size_t)s * 24]);
        fma4(acc2, n, yt[(size_t)p * 24]);
    }
    float ni = norm_in[d], no = norm_out[d];
    float4 bb = ((const float4*)b1)[tx];
    float4 aa = ((const float4*)a1)[tx];
    float4 r1 = prelu4(acc1, ni, bb, aa);
    float4 r2 = prelu4(acc2, ni, bb, aa);
    r1.x *= no; r1.y *= no; r1.z *= no; r1.w *= no;
    r2.x *= no; r2.y *= no; r2.z *= no; r2.w *= no;
    h1[(size_t)d * 24 + tx] = r1;
    h2[(size_t)d * 24 + tx] = r2;
}

// ---------------- layer-2 dual-view SpMM + fused final dot ----------------
__global__ __launch_bounds__(384) void spmm2_dual(
        const float4* __restrict__ t4,  // [2N,96]: view1 at 0, view2 at N*24 float4s
        const int* __restrict__ row_start, const int* __restrict__ csr_src,
        const int* __restrict__ order, const float* __restrict__ norm_in,
        const float* __restrict__ b2, const float* __restrict__ a2,
        const float* __restrict__ wsum, const float* __restrict__ bsum,
        float* __restrict__ outp, int N) {
    int g = blockIdx.x * 16 + threadIdx.y;
    int tx = threadIdx.x;
    int ty = threadIdx.y;
    bool valid = (g < N);
    int d = valid ? order[g] : 0;
    int beg = 0, end = 0;
    if (valid) { beg = row_start[d]; end = row_start[d + 1]; }
    const float4* t1 = t4 + tx;
    const float4* t2 = t4 + (size_t)N * 24 + tx;
    float4 acc1 = make_float4(0.f, 0.f, 0.f, 0.f);
    float4 acc2 = make_float4(0.f, 0.f, 0.f, 0.f);
    int j = beg;
    for (; j + 4 <= end; j += 4) {
        int s0 = csr_src[j], s1 = csr_src[j + 1], s2 = csr_src[j + 2], s3 = csr_src[j + 3];
        float4 u0 = t1[(size_t)s0 * 24], u1 = t1[(size_t)s1 * 24];
        float4 u2 = t1[(size_t)s2 * 24], u3 = t1[(size_t)s3 * 24];
        float4 w0 = t2[(size_t)s0 * 24], w1 = t2[(size_t)s1 * 24];
        float4 w2 = t2[(size_t)s2 * 24], w3 = t2[(size_t)s3 * 24];
        fma4(acc1, 1.f, u0); fma4(acc1, 1.f, u1); fma4(acc1, 1.f, u2); fma4(acc1, 1.f, u3);
        fma4(acc2, 1.f, w0); fma4(acc2, 1.f, w1); fma4(acc2, 1.f, w2); fma4(acc2, 1.f, w3);
    }
    for (; j < end; j++) {
        int s = csr_src[j];
        fma4(acc1, 1.f, t1[(size_t)s * 24]);
        fma4(acc2, 1.f, t2[(size_t)s * 24]);
    }
    float ni = valid ? norm_in[d] : 0.f;
    float4 bb = ((const float4*)b2)[tx];
    float4 aa = ((const float4*)a2)[tx];
    float4 wv = ((const float4*)wsum)[tx];
    float4 r1 = prelu4(acc1, ni, bb, aa);
    float4 r2 = prelu4(acc2, ni, bb, aa);
    float p1 = r1.x * wv.x + r1.y * wv.y + r1.z * wv.z + r1.w * wv.w;
    float p2 = r2.x * wv.x + r2.y * wv.y + r2.z * wv.z + r2.w * wv.w;
    __shared__ float red1[16][24];
    __shared__ float red2[16][24];
    red1[ty][tx] = p1;
    red2[ty][tx] = p2;
    __syncthreads();
    if (tx == 0 && valid) {
        float s1 = 0.f, s2 = 0.f;
#pragma unroll
        for (int k = 0; k < 24; k++) { s1 += red1[ty][k]; s2 += red2[ty][k]; }
        outp[d] = s1 + bsum[0];
        outp[N + d] = s2 + bsum[0];
    }
}

extern "C" void kernel_launch(void* const* d_in, const int* in_sizes, int n_in,
                              void* d_out, int out_size, void* d_ws, size_t ws_size,
                              hipStream_t stream) {
    const float* x    = (const float*)d_in[0];
    const int*   src  = (const int*)d_in[1];
    const int*   dst  = (const int*)d_in[2];
    const int*   perm = (const int*)d_in[3];
    const float* W1   = (const float*)d_in[4];
    const float* b1   = (const float*)d_in[5];
    const float* a1   = (const float*)d_in[6];
    const float* W2   = (const float*)d_in[7];
    const float* b2   = (const float*)d_in[8];
    const float* a2   = (const float*)d_in[9];
    const float* Wm   = (const float*)d_in[10];
    const float* bm   = (const float*)d_in[11];
    float* out = (float*)d_out;

    int E = in_sizes[1];
    int N = in_sizes[3];
    int F = in_sizes[0] / N;

    size_t NP = ((size_t)N + 256) & ~(size_t)255;  // >= N+1, multiple of 256
    size_t EP = ((size_t)E + 255) & ~(size_t)255;
    int* deg_out   = (int*)d_ws;          // NP
    int* deg_in    = deg_out + NP;        // NP
    int* pre       = deg_in + NP;         // NP
    int* row_start = pre + NP;            // NP
    int* cursor    = row_start + NP;      // NP
    int* order     = cursor + NP;         // NP
    int* bsums     = order + NP;          // 256
    int* hist      = bsums + 256;         // 256
    int* hcursor   = hist + 256;          // 256
    int* csr_src   = hcursor + 256;       // EP
    float* norm_out = (float*)(csr_src + EP);  // NP
    float* norm_in  = norm_out + NP;           // NP
    float* wsum     = norm_in + NP;            // 128
    float* bsum     = wsum + 128;              // 128
    float* tbuf     = bsum + 128;              // 2N*96 (first N*96 doubles as y)
    float* h1s      = tbuf + (size_t)2 * N * H96;  // 2N*96

    hipMemsetAsync(deg_out, 0, 2 * NP * sizeof(int), stream);
    hipMemsetAsync(hist, 0, 256 * sizeof(int), stream);
    deg_kernel<<<(E + 255) / 256, 256, 0, stream>>>(src, dst, deg_out, deg_in, E);
    norm_kernel<<<(N + 255) / 256, 256, 0, stream>>>(deg_out, deg_in, norm_out, norm_in, N);

    int nb = (N + 255) / 256;
    scan1_kernel<<<nb, 256, 0, stream>>>(deg_in, pre, bsums, N);
    scan2_kernel<<<1, 256, 0, stream>>>(bsums, nb);
    scan3_kernel<<<nb, 256, 0, stream>>>(pre, bsums, row_start, cursor, N, E);
    scatter_kernel<<<(E + 255) / 256, 256, 0, stream>>>(src, dst, cursor, csr_src, E);
    hist_kernel<<<nb, 256, 0, stream>>>(deg_in, hist, N);
    hist_scan_kernel<<<1, 256, 0, stream>>>(hist, hcursor);
    order_kernel<<<nb, 256, 0, stream>>>(deg_in, hcursor, order, N);
    wsum_kernel<<<1, 128, 0, stream>>>(Wm, bm, wsum, bsum);

    float* y = tbuf;  // reuse: y dead before tbuf is written
    // y = x @ W1 (shared across both views)
    gemm_kernel<<<(N + BM - 1) / BM, 256, 0, stream>>>(x, W1, y, N, F);

    // layer-1 dual SpMM -> h1s[2N,96]
    int nsb = (N + 15) / 16;
    spmm1_dual<<<nsb, dim3(24, 16), 0, stream>>>(
        (const float4*)y, row_start, csr_src, order, perm, norm_out, norm_in,
        b1, a1, (float4*)h1s, (float4*)(h1s + (size_t)N * H96), N);

    // tbuf[2N,96] = h1s[2N,96] @ W2  (overwrites y, which is dead now)
    gemm_kernel<<<(2 * N + BM - 1) / BM, 256, 0, stream>>>(h1s, W2, tbuf, 2 * N, H96);

    // layer-2 dual SpMM + fused final reduction -> out[2N]
    spmm2_dual<<<nsb, dim3(24, 16), 0, stream>>>(
        (const float4*)tbuf, row_start, csr_src, order, norm_in, b2, a2,
        wsum, bsum, out, N);
}

// Round 4
// 564.391 us; speedup vs baseline: 3.3035x; 1.4399x over previous
//
#include <hip/hip_runtime.h>

#define H96 96

// ---------------- degrees (int) ----------------
__global__ void deg_kernel(const int* __restrict__ src, const int* __restrict__ dst,
                           int* __restrict__ dout, int* __restrict__ din, int E) {
    int e = blockIdx.x * blockDim.x + threadIdx.x;
    if (e < E) {
        atomicAdd(dout + src[e], 1);
        atomicAdd(din + dst[e], 1);
    }
}

__global__ void norm_kernel(const int* __restrict__ dO, const int* __restrict__ dI,
                            float* __restrict__ no, float* __restrict__ ni, int N) {
    int i = blockIdx.x * blockDim.x + threadIdx.x;
    if (i < N) {
        no[i] = rsqrtf(fmaxf((float)dO[i], 1.0f));
        ni[i] = rsqrtf(fmaxf((float)dI[i], 1.0f));
    }
}

// ---------------- generic exclusive scan (3 kernels, n <= 256*256) ----------------
__global__ void scanA_kernel(const int* __restrict__ in, int* __restrict__ pre,
                             int* __restrict__ bsums, int n) {
    __shared__ int s[256];
    int i = blockIdx.x * 256 + threadIdx.x;
    int v = (i < n) ? in[i] : 0;
    s[threadIdx.x] = v;
    __syncthreads();
    for (int off = 1; off < 256; off <<= 1) {
        int t = (threadIdx.x >= off) ? s[threadIdx.x - off] : 0;
        __syncthreads();
        s[threadIdx.x] += t;
        __syncthreads();
    }
    if (i < n) pre[i] = s[threadIdx.x] - v;
    if (threadIdx.x == 255) bsums[blockIdx.x] = s[255];
}

__global__ void scanB_kernel(int* __restrict__ bsums, int nb) {
    __shared__ int s[256];
    int v = (threadIdx.x < nb) ? bsums[threadIdx.x] : 0;
    s[threadIdx.x] = v;
    __syncthreads();
    for (int off = 1; off < 256; off <<= 1) {
        int t = (threadIdx.x >= off) ? s[threadIdx.x - off] : 0;
        __syncthreads();
        s[threadIdx.x] += t;
        __syncthreads();
    }
    if (threadIdx.x < nb) bsums[threadIdx.x] = s[threadIdx.x] - v;
}

__global__ void scanC_kernel(const int* __restrict__ pre, const int* __restrict__ bsums,
                             int* __restrict__ out, int n) {
    int i = blockIdx.x * 256 + threadIdx.x;
    if (i < n) out[i] = pre[i] + bsums[blockIdx.x];
}

// row_start/cursor finalize (adds sentinel)
__global__ void rowfin_kernel(const int* __restrict__ pre, const int* __restrict__ bsums,
                              int* __restrict__ row_start, int* __restrict__ cursor,
                              int N, int E) {
    int i = blockIdx.x * 256 + threadIdx.x;
    if (i < N) {
        int v = pre[i] + bsums[blockIdx.x];
        row_start[i] = v;
        cursor[i] = v;
    }
    if (i == 0) row_start[N] = E;
}

// CSR scatter; also materialize per-slot perm-row and norm to shorten spmm1 dep chain
__global__ void scatter_kernel(const int* __restrict__ src, const int* __restrict__ dst,
                               const int* __restrict__ perm, const float* __restrict__ norm_out,
                               int* __restrict__ cursor, int* __restrict__ csr_src,
                               int* __restrict__ csr_perm, float* __restrict__ csr_norm, int E) {
    int e = blockIdx.x * 256 + threadIdx.x;
    if (e < E) {
        int d = dst[e];
        int s = src[e];
        int p = atomicAdd(cursor + d, 1);
        csr_src[p] = s;
        csr_perm[p] = perm[s];
        csr_norm[p] = norm_out[s];
    }
}

// ---------------- low-contention counting sort by deg_in ----------------
// hb[bin * nb + blk] = count of nodes in block blk with clamped degree bin
__global__ void histblk_kernel(const int* __restrict__ deg, int* __restrict__ hb,
                               int N, int nb) {
    __shared__ int h[256];
    h[threadIdx.x] = 0;
    __syncthreads();
    int i = blockIdx.x * 256 + threadIdx.x;
    if (i < N) atomicAdd(&h[min(deg[i], 255)], 1);
    __syncthreads();
    hb[threadIdx.x * nb + blockIdx.x] = h[threadIdx.x];
}

// place using scanned hb: LDS cursors per block
__global__ void place_kernel(const int* __restrict__ deg, const int* __restrict__ hbs,
                             int* __restrict__ order, int N, int nb) {
    __shared__ int cur[256];
    cur[threadIdx.x] = hbs[threadIdx.x * nb + blockIdx.x];
    __syncthreads();
    int i = blockIdx.x * 256 + threadIdx.x;
    if (i < N) {
        int b = min(deg[i], 255);
        int p = atomicAdd(&cur[b], 1);
        order[p] = i;
    }
}

// wsum[c] = row sums of Wm, bsum = sum(bm)
__global__ void wsum_kernel(const float* __restrict__ Wm, const float* __restrict__ bm,
                            float* __restrict__ wsum, float* __restrict__ bsum) {
    int c = threadIdx.x;
    if (c < H96) {
        float s = 0.f;
        for (int j = 0; j < H96; j++) s += Wm[c * H96 + j];
        wsum[c] = s;
    }
    if (c == 0) {
        float s = 0.f;
        for (int j = 0; j < H96; j++) s += bm[j];
        bsum[0] = s;
    }
}

// ---------------- fp32 GEMM: C[M,96] = A[M,K] @ B[K,96] ----------------
#define BM 128
#define BK 32
#define BKP 33
__global__ __launch_bounds__(256) void gemm_kernel(const float* __restrict__ A,
                                                   const float* __restrict__ B,
                                                   float* __restrict__ C, int M, int K) {
    __shared__ float As[BM * BKP];
    __shared__ float Bs[BK * H96];
    int tid = threadIdx.x;
    int tx = tid & 7, ty = tid >> 3;
    int row0 = blockIdx.x * BM;
    int r0 = ty * 4, c0 = tx * 12;
    alignas(16) float acc[4][12] = {};
    float4 pa[4], pb[3];
    int nk = (K + BK - 1) / BK;

#pragma unroll
    for (int i = 0; i < 4; i++) {
        int idx = tid + i * 256;
        int r = idx >> 3, kq = idx & 7;
        int gr = row0 + r, gk = kq * 4;
        pa[i] = (gr < M && gk < K) ? *(const float4*)(A + (size_t)gr * K + gk)
                                   : make_float4(0.f, 0.f, 0.f, 0.f);
    }
#pragma unroll
    for (int i = 0; i < 3; i++) {
        int idx = tid + i * 256;
        int kk = idx / 24, cq = idx - kk * 24;
        pb[i] = (kk < K) ? *(const float4*)(B + (size_t)kk * H96 + cq * 4)
                         : make_float4(0.f, 0.f, 0.f, 0.f);
    }

    for (int t = 0; t < nk; t++) {
#pragma unroll
        for (int i = 0; i < 4; i++) {
            int idx = tid + i * 256;
            int r = idx >> 3, kq = idx & 7;
            As[r * BKP + kq * 4 + 0] = pa[i].x;
            As[r * BKP + kq * 4 + 1] = pa[i].y;
            As[r * BKP + kq * 4 + 2] = pa[i].z;
            As[r * BKP + kq * 4 + 3] = pa[i].w;
        }
#pragma unroll
        for (int i = 0; i < 3; i++) {
            int idx = tid + i * 256;
            int kk = idx / 24, cq = idx - kk * 24;
            *(float4*)(&Bs[kk * H96 + cq * 4]) = pb[i];
        }
        __syncthreads();

        if (t + 1 < nk) {
            int k0 = (t + 1) * BK;
#pragma unroll
            for (int i = 0; i < 4; i++) {
                int idx = tid + i * 256;
                int r = idx >> 3, kq = idx & 7;
                int gr = row0 + r, gk = k0 + kq * 4;
                pa[i] = (gr < M && gk < K) ? *(const float4*)(A + (size_t)gr * K + gk)
                                           : make_float4(0.f, 0.f, 0.f, 0.f);
            }
#pragma unroll
            for (int i = 0; i < 3; i++) {
                int idx = tid + i * 256;
                int kk = idx / 24, cq = idx - kk * 24;
                int gk = k0 + kk;
                pb[i] = (gk < K) ? *(const float4*)(B + (size_t)gk * H96 + cq * 4)
                                 : make_float4(0.f, 0.f, 0.f, 0.f);
            }
        }

#pragma unroll 8
        for (int k = 0; k < BK; k++) {
            float a[4];
            alignas(16) float b[12];
#pragma unroll
            for (int i = 0; i < 4; i++) a[i] = As[(r0 + i) * BKP + k];
#pragma unroll
            for (int j = 0; j < 3; j++)
                *(float4*)&b[j * 4] = *(const float4*)&Bs[k * H96 + c0 + j * 4];
#pragma unroll
            for (int i = 0; i < 4; i++)
#pragma unroll
                for (int j = 0; j < 12; j++)
                    acc[i][j] = fmaf(a[i], b[j], acc[i][j]);
        }
        __syncthreads();
    }

#pragma unroll
    for (int i = 0; i < 4; i++) {
        int gr = row0 + r0 + i;
        if (gr < M) {
#pragma unroll
            for (int j = 0; j < 3; j++)
                *(float4*)(C + (size_t)gr * H96 + c0 + j * 4) = *(const float4*)&acc[i][j * 4];
        }
    }
}

// ---------------- helpers ----------------
__device__ __forceinline__ void fma4(float4& a, float s, const float4& v) {
    a.x = fmaf(s, v.x, a.x);
    a.y = fmaf(s, v.y, a.y);
    a.z = fmaf(s, v.z, a.z);
    a.w = fmaf(s, v.w, a.w);
}

__device__ __forceinline__ float4 prelu4(float4 acc, float ni, float4 b, float4 a) {
    float4 h;
    h.x = fmaf(acc.x, ni, b.x); h.x = (h.x >= 0.f) ? h.x : a.x * h.x;
    h.y = fmaf(acc.y, ni, b.y); h.y = (h.y >= 0.f) ? h.y : a.y * h.y;
    h.z = fmaf(acc.z, ni, b.z); h.z = (h.z >= 0.f) ? h.z : a.z * h.z;
    h.w = fmaf(acc.w, ni, b.w); h.w = (h.w >= 0.f) ? h.w : a.w * h.w;
    return h;
}

// ---------------- layer-1 dual-view SpMM, float4, 4-edge unroll ----------------
__global__ __launch_bounds__(384) void spmm1_dual(
        const float4* __restrict__ y4, const int* __restrict__ row_start,
        const int* __restrict__ csr_src, const int* __restrict__ csr_perm,
        const float* __restrict__ csr_norm, const int* __restrict__ order,
        const float* __restrict__ norm_out, const float* __restrict__ norm_in,
        const float* __restrict__ b1, const float* __restrict__ a1,
        float4* __restrict__ h1, float4* __restrict__ h2, int N) {
    int g = blockIdx.x * 16 + threadIdx.y;
    if (g >= N) return;
    int d = order[g];
    int tx = threadIdx.x;
    int beg = row_start[d], end = row_start[d + 1];
    const float4* yt = y4 + tx;
    float4 acc1 = make_float4(0.f, 0.f, 0.f, 0.f);
    float4 acc2 = make_float4(0.f, 0.f, 0.f, 0.f);
    int j = beg;
    for (; j + 4 <= end; j += 4) {
        int s0 = csr_src[j], s1 = csr_src[j + 1], s2 = csr_src[j + 2], s3 = csr_src[j + 3];
        int p0 = csr_perm[j], p1 = csr_perm[j + 1], p2 = csr_perm[j + 2], p3 = csr_perm[j + 3];
        float n0 = csr_norm[j], n1 = csr_norm[j + 1], n2 = csr_norm[j + 2], n3 = csr_norm[j + 3];
        float4 u0 = yt[(size_t)s0 * 24], u1 = yt[(size_t)s1 * 24];
        float4 u2 = yt[(size_t)s2 * 24], u3 = yt[(size_t)s3 * 24];
        float4 w0 = yt[(size_t)p0 * 24], w1 = yt[(size_t)p1 * 24];
        float4 w2 = yt[(size_t)p2 * 24], w3 = yt[(size_t)p3 * 24];
        fma4(acc1, n0, u0); fma4(acc1, n1, u1); fma4(acc1, n2, u2); fma4(acc1, n3, u3);
        fma4(acc2, n0, w0); fma4(acc2, n1, w1); fma4(acc2, n2, w2); fma4(acc2, n3, w3);
    }
    for (; j < end; j++) {
        int s = csr_src[j];
        int p = csr_perm[j];
        float n = csr_norm[j];
        fma4(acc1, n, yt[(size_t)s * 24]);
        fma4(acc2, n, yt[(size_t)p * 24]);
    }
    float ni = norm_in[d], no = norm_out[d];
    float4 bb = ((const float4*)b1)[tx];
    float4 aa = ((const float4*)a1)[tx];
    float4 r1 = prelu4(acc1, ni, bb, aa);
    float4 r2 = prelu4(acc2, ni, bb, aa);
    r1.x *= no; r1.y *= no; r1.z *= no; r1.w *= no;
    r2.x *= no; r2.y *= no; r2.z *= no; r2.w *= no;
    h1[(size_t)d * 24 + tx] = r1;
    h2[(size_t)d * 24 + tx] = r2;
}

// ---------------- layer-2 dual-view SpMM + fused final dot ----------------
__global__ __launch_bounds__(384) void spmm2_dual(
        const float4* __restrict__ t4,
        const int* __restrict__ row_start, const int* __restrict__ csr_src,
        const int* __restrict__ order, const float* __restrict__ norm_in,
        const float* __restrict__ b2, const float* __restrict__ a2,
        const float* __restrict__ wsum, const float* __restrict__ bsum,
        float* __restrict__ outp, int N) {
    int g = blockIdx.x * 16 + threadIdx.y;
    int tx = threadIdx.x;
    int ty = threadIdx.y;
    bool valid = (g < N);
    int d = valid ? order[g] : 0;
    int beg = 0, end = 0;
    if (valid) { beg = row_start[d]; end = row_start[d + 1]; }
    const float4* t1 = t4 + tx;
    const float4* t2 = t4 + (size_t)N * 24 + tx;
    float4 acc1 = make_float4(0.f, 0.f, 0.f, 0.f);
    float4 acc2 = make_float4(0.f, 0.f, 0.f, 0.f);
    int j = beg;
    for (; j + 4 <= end; j += 4) {
        int s0 = csr_src[j], s1 = csr_src[j + 1], s2 = csr_src[j + 2], s3 = csr_src[j + 3];
        float4 u0 = t1[(size_t)s0 * 24], u1 = t1[(size_t)s1 * 24];
        float4 u2 = t1[(size_t)s2 * 24], u3 = t1[(size_t)s3 * 24];
        float4 w0 = t2[(size_t)s0 * 24], w1 = t2[(size_t)s1 * 24];
        float4 w2 = t2[(size_t)s2 * 24], w3 = t2[(size_t)s3 * 24];
        fma4(acc1, 1.f, u0); fma4(acc1, 1.f, u1); fma4(acc1, 1.f, u2); fma4(acc1, 1.f, u3);
        fma4(acc2, 1.f, w0); fma4(acc2, 1.f, w1); fma4(acc2, 1.f, w2); fma4(acc2, 1.f, w3);
    }
    for (; j < end; j++) {
        int s = csr_src[j];
        fma4(acc1, 1.f, t1[(size_t)s * 24]);
        fma4(acc2, 1.f, t2[(size_t)s * 24]);
    }
    float ni = valid ? norm_in[d] : 0.f;
    float4 bb = ((const float4*)b2)[tx];
    float4 aa = ((const float4*)a2)[tx];
    float4 wv = ((const float4*)wsum)[tx];
    float4 r1 = prelu4(acc1, ni, bb, aa);
    float4 r2 = prelu4(acc2, ni, bb, aa);
    float p1 = r1.x * wv.x + r1.y * wv.y + r1.z * wv.z + r1.w * wv.w;
    float p2 = r2.x * wv.x + r2.y * wv.y + r2.z * wv.z + r2.w * wv.w;
    __shared__ float red1[16][24];
    __shared__ float red2[16][24];
    red1[ty][tx] = p1;
    red2[ty][tx] = p2;
    __syncthreads();
    if (tx == 0 && valid) {
        float s1 = 0.f, s2 = 0.f;
#pragma unroll
        for (int k = 0; k < 24; k++) { s1 += red1[ty][k]; s2 += red2[ty][k]; }
        outp[d] = s1 + bsum[0];
        outp[N + d] = s2 + bsum[0];
    }
}

extern "C" void kernel_launch(void* const* d_in, const int* in_sizes, int n_in,
                              void* d_out, int out_size, void* d_ws, size_t ws_size,
                              hipStream_t stream) {
    const float* x    = (const float*)d_in[0];
    const int*   src  = (const int*)d_in[1];
    const int*   dst  = (const int*)d_in[2];
    const int*   perm = (const int*)d_in[3];
    const float* W1   = (const float*)d_in[4];
    const float* b1   = (const float*)d_in[5];
    const float* a1   = (const float*)d_in[6];
    const float* W2   = (const float*)d_in[7];
    const float* b2   = (const float*)d_in[8];
    const float* a2   = (const float*)d_in[9];
    const float* Wm   = (const float*)d_in[10];
    const float* bm   = (const float*)d_in[11];
    float* out = (float*)d_out;

    int E = in_sizes[1];
    int N = in_sizes[3];
    int F = in_sizes[0] / N;

    size_t NP = ((size_t)N + 256) & ~(size_t)255;  // >= N+1, multiple of 256
    size_t EP = ((size_t)E + 255) & ~(size_t)255;
    int nb = (N + 255) / 256;
    size_t HB = ((size_t)256 * nb + 255) & ~(size_t)255;

    int* deg_out   = (int*)d_ws;          // NP
    int* deg_in    = deg_out + NP;        // NP
    int* pre       = deg_in + NP;         // NP (also reused for hb scan partials)
    int* row_start = pre + NP;            // NP
    int* cursor    = row_start + NP;      // NP
    int* order     = cursor + NP;         // NP
    int* bsums     = order + NP;          // 256
    int* hb        = bsums + 256;         // HB
    int* hbs       = hb + HB;             // HB
    int* hpre      = hbs + HB;            // HB
    int* csr_src   = hpre + HB;           // EP
    int* csr_perm  = csr_src + EP;        // EP
    float* csr_norm = (float*)(csr_perm + EP); // EP
    float* norm_out = csr_norm + EP;           // NP
    float* norm_in  = norm_out + NP;           // NP
    float* wsum     = norm_in + NP;            // 128
    float* bsum     = wsum + 128;              // 128
    float* tbuf     = bsum + 128;              // 2N*96 (first N*96 doubles as y)
    float* h1s      = tbuf + (size_t)2 * N * H96;  // 2N*96

    hipMemsetAsync(deg_out, 0, 2 * NP * sizeof(int), stream);
    deg_kernel<<<(E + 255) / 256, 256, 0, stream>>>(src, dst, deg_out, deg_in, E);
    norm_kernel<<<(N + 255) / 256, 256, 0, stream>>>(deg_out, deg_in, norm_out, norm_in, N);

    // row_start = exscan(deg_in); cursor = copy
    scanA_kernel<<<nb, 256, 0, stream>>>(deg_in, pre, bsums, N);
    scanB_kernel<<<1, 256, 0, stream>>>(bsums, nb);
    rowfin_kernel<<<nb, 256, 0, stream>>>(pre, bsums, row_start, cursor, N, E);
    scatter_kernel<<<(E + 255) / 256, 256, 0, stream>>>(src, dst, perm, norm_out, cursor,
                                                        csr_src, csr_perm, csr_norm, E);

    // low-contention counting sort by deg_in -> order
    histblk_kernel<<<nb, 256, 0, stream>>>(deg_in, hb, N, nb);
    int n2 = 256 * nb;
    int nb2 = (n2 + 255) / 256;
    scanA_kernel<<<nb2, 256, 0, stream>>>(hb, hpre, bsums, n2);
    scanB_kernel<<<1, 256, 0, stream>>>(bsums, nb2);
    scanC_kernel<<<nb2, 256, 0, stream>>>(hpre, bsums, hbs, n2);
    place_kernel<<<nb, 256, 0, stream>>>(deg_in, hbs, order, N, nb);

    wsum_kernel<<<1, 128, 0, stream>>>(Wm, bm, wsum, bsum);

    float* y = tbuf;  // reuse: y dead before tbuf is written
    gemm_kernel<<<(N + BM - 1) / BM, 256, 0, stream>>>(x, W1, y, N, F);

    int nsb = (N + 15) / 16;
    spmm1_dual<<<nsb, dim3(24, 16), 0, stream>>>(
        (const float4*)y, row_start, csr_src, csr_perm, csr_norm, order, norm_out, norm_in,
        b1, a1, (float4*)h1s, (float4*)(h1s + (size_t)N * H96), N);

    gemm_kernel<<<(2 * N + BM - 1) / BM, 256, 0, stream>>>(h1s, W2, tbuf, 2 * N, H96);

    spmm2_dual<<<nsb, dim3(24, 16), 0, stream>>>(
        (const float4*)tbuf, row_start, csr_src, order, norm_in, b2, a2,
        wsum, bsum, out, N);
}

// Round 5
// 561.592 us; speedup vs baseline: 3.3199x; 1.0050x over previous
//
#include <hip/hip_runtime.h>

#define H96 96

// ---------------- degrees (int) ----------------
__global__ void deg_kernel(const int* __restrict__ src, const int* __restrict__ dst,
                           int* __restrict__ dout, int* __restrict__ din, int E) {
    int e = blockIdx.x * blockDim.x + threadIdx.x;
    if (e < E) {
        atomicAdd(dout + src[e], 1);
        atomicAdd(din + dst[e], 1);
    }
}

__global__ void norm_kernel(const int* __restrict__ dO, const int* __restrict__ dI,
                            float* __restrict__ no, float* __restrict__ ni, int N) {
    int i = blockIdx.x * blockDim.x + threadIdx.x;
    if (i < N) {
        no[i] = rsqrtf(fmaxf((float)dO[i], 1.0f));
        ni[i] = rsqrtf(fmaxf((float)dI[i], 1.0f));
    }
}

// ---------------- generic exclusive scan (3 kernels, n <= 256*256) ----------------
__global__ void scanA_kernel(const int* __restrict__ in, int* __restrict__ pre,
                             int* __restrict__ bsums, int n) {
    __shared__ int s[256];
    int i = blockIdx.x * 256 + threadIdx.x;
    int v = (i < n) ? in[i] : 0;
    s[threadIdx.x] = v;
    __syncthreads();
    for (int off = 1; off < 256; off <<= 1) {
        int t = (threadIdx.x >= off) ? s[threadIdx.x - off] : 0;
        __syncthreads();
        s[threadIdx.x] += t;
        __syncthreads();
    }
    if (i < n) pre[i] = s[threadIdx.x] - v;
    if (threadIdx.x == 255) bsums[blockIdx.x] = s[255];
}

__global__ void scanB_kernel(int* __restrict__ bsums, int nb) {
    __shared__ int s[256];
    int v = (threadIdx.x < nb) ? bsums[threadIdx.x] : 0;
    s[threadIdx.x] = v;
    __syncthreads();
    for (int off = 1; off < 256; off <<= 1) {
        int t = (threadIdx.x >= off) ? s[threadIdx.x - off] : 0;
        __syncthreads();
        s[threadIdx.x] += t;
        __syncthreads();
    }
    if (threadIdx.x < nb) bsums[threadIdx.x] = s[threadIdx.x] - v;
}

__global__ void scanC_kernel(const int* __restrict__ pre, const int* __restrict__ bsums,
                             int* __restrict__ out, int n) {
    int i = blockIdx.x * 256 + threadIdx.x;
    if (i < n) out[i] = pre[i] + bsums[blockIdx.x];
}

// row_start/cursor finalize (adds sentinel)
__global__ void rowfin_kernel(const int* __restrict__ pre, const int* __restrict__ bsums,
                              int* __restrict__ row_start, int* __restrict__ cursor,
                              int N, int E) {
    int i = blockIdx.x * 256 + threadIdx.x;
    if (i < N) {
        int v = pre[i] + bsums[blockIdx.x];
        row_start[i] = v;
        cursor[i] = v;
    }
    if (i == 0) row_start[N] = E;
}

// CSR scatter; also materialize per-slot perm-row and norm to shorten spmm1 dep chain
__global__ void scatter_kernel(const int* __restrict__ src, const int* __restrict__ dst,
                               const int* __restrict__ perm, const float* __restrict__ norm_out,
                               int* __restrict__ cursor, int* __restrict__ csr_src,
                               int* __restrict__ csr_perm, float* __restrict__ csr_norm, int E) {
    int e = blockIdx.x * 256 + threadIdx.x;
    if (e < E) {
        int d = dst[e];
        int s = src[e];
        int p = atomicAdd(cursor + d, 1);
        csr_src[p] = s;
        csr_perm[p] = perm[s];
        csr_norm[p] = norm_out[s];
    }
}

// ---------------- low-contention counting sort by deg_in ----------------
__global__ void histblk_kernel(const int* __restrict__ deg, int* __restrict__ hb,
                               int N, int nb) {
    __shared__ int h[256];
    h[threadIdx.x] = 0;
    __syncthreads();
    int i = blockIdx.x * 256 + threadIdx.x;
    if (i < N) atomicAdd(&h[min(deg[i], 255)], 1);
    __syncthreads();
    hb[threadIdx.x * nb + blockIdx.x] = h[threadIdx.x];
}

__global__ void place_kernel(const int* __restrict__ deg, const int* __restrict__ hbs,
                             int* __restrict__ order, int N, int nb) {
    __shared__ int cur[256];
    cur[threadIdx.x] = hbs[threadIdx.x * nb + blockIdx.x];
    __syncthreads();
    int i = blockIdx.x * 256 + threadIdx.x;
    if (i < N) {
        int b = min(deg[i], 255);
        int p = atomicAdd(&cur[b], 1);
        order[p] = i;
    }
}

// wsum[c] = row sums of Wm, bsum = sum(bm)
__global__ void wsum_kernel(const float* __restrict__ Wm, const float* __restrict__ bm,
                            float* __restrict__ wsum, float* __restrict__ bsum) {
    int c = threadIdx.x;
    if (c < H96) {
        float s = 0.f;
        for (int j = 0; j < H96; j++) s += Wm[c * H96 + j];
        wsum[c] = s;
    }
    if (c == 0) {
        float s = 0.f;
        for (int j = 0; j < H96; j++) s += bm[j];
        bsum[0] = s;
    }
}

// ---------------- fp32 GEMM: C[M,96] = A[M,K] @ B[K,96], BM=64 for grid parallelism ----------------
#define BM 64
#define BK 32
#define BKP 33
__global__ __launch_bounds__(256) void gemm_kernel(const float* __restrict__ A,
                                                   const float* __restrict__ B,
                                                   float* __restrict__ C, int M, int K) {
    __shared__ float As[BM * BKP];   // 64 x 33 = 8.4 KB
    __shared__ float Bs[BK * H96];   // 32 x 96 = 12 KB
    int tid = threadIdx.x;
    int tx = tid & 7, ty = tid >> 3;     // 8 col groups x 32 row groups
    int row0 = blockIdx.x * BM;
    int r0 = ty * 2, c0 = tx * 12;       // 2 rows x 12 cols per thread
    alignas(16) float acc[2][12] = {};
    float4 pa[2], pb[3];
    int nk = (K + BK - 1) / BK;

    // stage tile 0 into regs (A: 64x32 = 512 float4, 2/thread; B: 768 float4, 3/thread)
#pragma unroll
    for (int i = 0; i < 2; i++) {
        int idx = tid + i * 256;
        int r = idx >> 3, kq = idx & 7;
        int gr = row0 + r, gk = kq * 4;
        pa[i] = (gr < M && gk < K) ? *(const float4*)(A + (size_t)gr * K + gk)
                                   : make_float4(0.f, 0.f, 0.f, 0.f);
    }
#pragma unroll
    for (int i = 0; i < 3; i++) {
        int idx = tid + i * 256;
        int kk = idx / 24, cq = idx - kk * 24;
        pb[i] = (kk < K) ? *(const float4*)(B + (size_t)kk * H96 + cq * 4)
                         : make_float4(0.f, 0.f, 0.f, 0.f);
    }

    for (int t = 0; t < nk; t++) {
#pragma unroll
        for (int i = 0; i < 2; i++) {
            int idx = tid + i * 256;
            int r = idx >> 3, kq = idx & 7;
            As[r * BKP + kq * 4 + 0] = pa[i].x;
            As[r * BKP + kq * 4 + 1] = pa[i].y;
            As[r * BKP + kq * 4 + 2] = pa[i].z;
            As[r * BKP + kq * 4 + 3] = pa[i].w;
        }
#pragma unroll
        for (int i = 0; i < 3; i++) {
            int idx = tid + i * 256;
            int kk = idx / 24, cq = idx - kk * 24;
            *(float4*)(&Bs[kk * H96 + cq * 4]) = pb[i];
        }
        __syncthreads();

        if (t + 1 < nk) {
            int k0 = (t + 1) * BK;
#pragma unroll
            for (int i = 0; i < 2; i++) {
                int idx = tid + i * 256;
                int r = idx >> 3, kq = idx & 7;
                int gr = row0 + r, gk = k0 + kq * 4;
                pa[i] = (gr < M && gk < K) ? *(const float4*)(A + (size_t)gr * K + gk)
                                           : make_float4(0.f, 0.f, 0.f, 0.f);
            }
#pragma unroll
            for (int i = 0; i < 3; i++) {
                int idx = tid + i * 256;
                int kk = idx / 24, cq = idx - kk * 24;
                int gk = k0 + kk;
                pb[i] = (gk < K) ? *(const float4*)(B + (size_t)gk * H96 + cq * 4)
                                 : make_float4(0.f, 0.f, 0.f, 0.f);
            }
        }

#pragma unroll 8
        for (int k = 0; k < BK; k++) {
            float a0 = As[(r0 + 0) * BKP + k];
            float a1 = As[(r0 + 1) * BKP + k];
            alignas(16) float b[12];
#pragma unroll
            for (int j = 0; j < 3; j++)
                *(float4*)&b[j * 4] = *(const float4*)&Bs[k * H96 + c0 + j * 4];
#pragma unroll
            for (int j = 0; j < 12; j++) {
                acc[0][j] = fmaf(a0, b[j], acc[0][j]);
                acc[1][j] = fmaf(a1, b[j], acc[1][j]);
            }
        }
        __syncthreads();
    }

#pragma unroll
    for (int i = 0; i < 2; i++) {
        int gr = row0 + r0 + i;
        if (gr < M) {
#pragma unroll
            for (int j = 0; j < 3; j++)
                *(float4*)(C + (size_t)gr * H96 + c0 + j * 4) = *(const float4*)&acc[i][j * 4];
        }
    }
}

// ---------------- helpers ----------------
__device__ __forceinline__ void fma4(float4& a, float s, const float4& v) {
    a.x = fmaf(s, v.x, a.x);
    a.y = fmaf(s, v.y, a.y);
    a.z = fmaf(s, v.z, a.z);
    a.w = fmaf(s, v.w, a.w);
}

__device__ __forceinline__ float4 prelu4(float4 acc, float ni, float4 b, float4 a) {
    float4 h;
    h.x = fmaf(acc.x, ni, b.x); h.x = (h.x >= 0.f) ? h.x : a.x * h.x;
    h.y = fmaf(acc.y, ni, b.y); h.y = (h.y >= 0.f) ? h.y : a.y * h.y;
    h.z = fmaf(acc.z, ni, b.z); h.z = (h.z >= 0.f) ? h.z : a.z * h.z;
    h.w = fmaf(acc.w, ni, b.w); h.w = (h.w >= 0.f) ? h.w : a.w * h.w;
    return h;
}

// ---------------- layer-1 dual-view SpMM, float4, 4-edge unroll ----------------
__global__ __launch_bounds__(384) void spmm1_dual(
        const float4* __restrict__ y4, const int* __restrict__ row_start,
        const int* __restrict__ csr_src, const int* __restrict__ csr_perm,
        const float* __restrict__ csr_norm, const int* __restrict__ order,
        const float* __restrict__ norm_out, const float* __restrict__ norm_in,
        const float* __restrict__ b1, const float* __restrict__ a1,
        float4* __restrict__ h1, float4* __restrict__ h2, int N) {
    int g = blockIdx.x * 16 + threadIdx.y;
    if (g >= N) return;
    int d = order[g];
    int tx = threadIdx.x;
    int beg = row_start[d], end = row_start[d + 1];
    const float4* yt = y4 + tx;
    float4 acc1 = make_float4(0.f, 0.f, 0.f, 0.f);
    float4 acc2 = make_float4(0.f, 0.f, 0.f, 0.f);
    int j = beg;
    for (; j + 4 <= end; j += 4) {
        int s0 = csr_src[j], s1 = csr_src[j + 1], s2 = csr_src[j + 2], s3 = csr_src[j + 3];
        int p0 = csr_perm[j], p1 = csr_perm[j + 1], p2 = csr_perm[j + 2], p3 = csr_perm[j + 3];
        float n0 = csr_norm[j], n1 = csr_norm[j + 1], n2 = csr_norm[j + 2], n3 = csr_norm[j + 3];
        float4 u0 = yt[(size_t)s0 * 24], u1 = yt[(size_t)s1 * 24];
        float4 u2 = yt[(size_t)s2 * 24], u3 = yt[(size_t)s3 * 24];
        float4 w0 = yt[(size_t)p0 * 24], w1 = yt[(size_t)p1 * 24];
        float4 w2 = yt[(size_t)p2 * 24], w3 = yt[(size_t)p3 * 24];
        fma4(acc1, n0, u0); fma4(acc1, n1, u1); fma4(acc1, n2, u2); fma4(acc1, n3, u3);
        fma4(acc2, n0, w0); fma4(acc2, n1, w1); fma4(acc2, n2, w2); fma4(acc2, n3, w3);
    }
    for (; j < end; j++) {
        int s = csr_src[j];
        int p = csr_perm[j];
        float n = csr_norm[j];
        fma4(acc1, n, yt[(size_t)s * 24]);
        fma4(acc2, n, yt[(size_t)p * 24]);
    }
    float ni = norm_in[d], no = norm_out[d];
    float4 bb = ((const float4*)b1)[tx];
    float4 aa = ((const float4*)a1)[tx];
    float4 r1 = prelu4(acc1, ni, bb, aa);
    float4 r2 = prelu4(acc2, ni, bb, aa);
    r1.x *= no; r1.y *= no; r1.z *= no; r1.w *= no;
    r2.x *= no; r2.y *= no; r2.z *= no; r2.w *= no;
    h1[(size_t)d * 24 + tx] = r1;
    h2[(size_t)d * 24 + tx] = r2;
}

// ---------------- layer-2 dual-view SpMM + fused final dot ----------------
__global__ __launch_bounds__(384) void spmm2_dual(
        const float4* __restrict__ t4,
        const int* __restrict__ row_start, const int* __restrict__ csr_src,
        const int* __restrict__ order, const float* __restrict__ norm_in,
        const float* __restrict__ b2, const float* __restrict__ a2,
        const float* __restrict__ wsum, const float* __restrict__ bsum,
        float* __restrict__ outp, int N) {
    int g = blockIdx.x * 16 + threadIdx.y;
    int tx = threadIdx.x;
    int ty = threadIdx.y;
    bool valid = (g < N);
    int d = valid ? order[g] : 0;
    int beg = 0, end = 0;
    if (valid) { beg = row_start[d]; end = row_start[d + 1]; }
    const float4* t1 = t4 + tx;
    const float4* t2 = t4 + (size_t)N * 24 + tx;
    float4 acc1 = make_float4(0.f, 0.f, 0.f, 0.f);
    float4 acc2 = make_float4(0.f, 0.f, 0.f, 0.f);
    int j = beg;
    for (; j + 4 <= end; j += 4) {
        int s0 = csr_src[j], s1 = csr_src[j + 1], s2 = csr_src[j + 2], s3 = csr_src[j + 3];
        float4 u0 = t1[(size_t)s0 * 24], u1 = t1[(size_t)s1 * 24];
        float4 u2 = t1[(size_t)s2 * 24], u3 = t1[(size_t)s3 * 24];
        float4 w0 = t2[(size_t)s0 * 24], w1 = t2[(size_t)s1 * 24];
        float4 w2 = t2[(size_t)s2 * 24], w3 = t2[(size_t)s3 * 24];
        fma4(acc1, 1.f, u0); fma4(acc1, 1.f, u1); fma4(acc1, 1.f, u2); fma4(acc1, 1.f, u3);
        fma4(acc2, 1.f, w0); fma4(acc2, 1.f, w1); fma4(acc2, 1.f, w2); fma4(acc2, 1.f, w3);
    }
    for (; j < end; j++) {
        int s = csr_src[j];
        fma4(acc1, 1.f, t1[(size_t)s * 24]);
        fma4(acc2, 1.f, t2[(size_t)s * 24]);
    }
    float ni = valid ? norm_in[d] : 0.f;
    float4 bb = ((const float4*)b2)[tx];
    float4 aa = ((const float4*)a2)[tx];
    float4 wv = ((const float4*)wsum)[tx];
    float4 r1 = prelu4(acc1, ni, bb, aa);
    float4 r2 = prelu4(acc2, ni, bb, aa);
    float p1 = r1.x * wv.x + r1.y * wv.y + r1.z * wv.z + r1.w * wv.w;
    float p2 = r2.x * wv.x + r2.y * wv.y + r2.z * wv.z + r2.w * wv.w;
    __shared__ float red1[16][24];
    __shared__ float red2[16][24];
    red1[ty][tx] = p1;
    red2[ty][tx] = p2;
    __syncthreads();
    if (tx == 0 && valid) {
        float s1 = 0.f, s2 = 0.f;
#pragma unroll
        for (int k = 0; k < 24; k++) { s1 += red1[ty][k]; s2 += red2[ty][k]; }
        outp[d] = s1 + bsum[0];
        outp[N + d] = s2 + bsum[0];
    }
}

extern "C" void kernel_launch(void* const* d_in, const int* in_sizes, int n_in,
                              void* d_out, int out_size, void* d_ws, size_t ws_size,
                              hipStream_t stream) {
    const float* x    = (const float*)d_in[0];
    const int*   src  = (const int*)d_in[1];
    const int*   dst  = (const int*)d_in[2];
    const int*   perm = (const int*)d_in[3];
    const float* W1   = (const float*)d_in[4];
    const float* b1   = (const float*)d_in[5];
    const float* a1   = (const float*)d_in[6];
    const float* W2   = (const float*)d_in[7];
    const float* b2   = (const float*)d_in[8];
    const float* a2   = (const float*)d_in[9];
    const float* Wm   = (const float*)d_in[10];
    const float* bm   = (const float*)d_in[11];
    float* out = (float*)d_out;

    int E = in_sizes[1];
    int N = in_sizes[3];
    int F = in_sizes[0] / N;

    size_t NP = ((size_t)N + 256) & ~(size_t)255;  // >= N+1, multiple of 256
    size_t EP = ((size_t)E + 255) & ~(size_t)255;
    int nb = (N + 255) / 256;
    size_t HB = ((size_t)256 * nb + 255) & ~(size_t)255;

    int* deg_out   = (int*)d_ws;          // NP
    int* deg_in    = deg_out + NP;        // NP
    int* pre       = deg_in + NP;         // NP
    int* row_start = pre + NP;            // NP
    int* cursor    = row_start + NP;      // NP
    int* order     = cursor + NP;         // NP
    int* bsums     = order + NP;          // 256
    int* hb        = bsums + 256;         // HB
    int* hbs       = hb + HB;             // HB
    int* hpre      = hbs + HB;            // HB
    int* csr_src   = hpre + HB;           // EP
    int* csr_perm  = csr_src + EP;        // EP
    float* csr_norm = (float*)(csr_perm + EP); // EP
    float* norm_out = csr_norm + EP;           // NP
    float* norm_in  = norm_out + NP;           // NP
    float* wsum     = norm_in + NP;            // 128
    float* bsum     = wsum + 128;              // 128
    float* tbuf     = bsum + 128;              // 2N*96 (first N*96 doubles as y)
    float* h1s      = tbuf + (size_t)2 * N * H96;  // 2N*96

    hipMemsetAsync(deg_out, 0, 2 * NP * sizeof(int), stream);
    deg_kernel<<<(E + 255) / 256, 256, 0, stream>>>(src, dst, deg_out, deg_in, E);
    norm_kernel<<<(N + 255) / 256, 256, 0, stream>>>(deg_out, deg_in, norm_out, norm_in, N);

    scanA_kernel<<<nb, 256, 0, stream>>>(deg_in, pre, bsums, N);
    scanB_kernel<<<1, 256, 0, stream>>>(bsums, nb);
    rowfin_kernel<<<nb, 256, 0, stream>>>(pre, bsums, row_start, cursor, N, E);
    scatter_kernel<<<(E + 255) / 256, 256, 0, stream>>>(src, dst, perm, norm_out, cursor,
                                                        csr_src, csr_perm, csr_norm, E);

    histblk_kernel<<<nb, 256, 0, stream>>>(deg_in, hb, N, nb);
    int n2 = 256 * nb;
    int nb2 = (n2 + 255) / 256;
    scanA_kernel<<<nb2, 256, 0, stream>>>(hb, hpre, bsums, n2);
    scanB_kernel<<<1, 256, 0, stream>>>(bsums, nb2);
    scanC_kernel<<<nb2, 256, 0, stream>>>(hpre, bsums, hbs, n2);
    place_kernel<<<nb, 256, 0, stream>>>(deg_in, hbs, order, N, nb);

    wsum_kernel<<<1, 128, 0, stream>>>(Wm, bm, wsum, bsum);

    float* y = tbuf;  // reuse: y dead before tbuf is written
    gemm_kernel<<<(N + BM - 1) / BM, 256, 0, stream>>>(x, W1, y, N, F);

    int nsb = (N + 15) / 16;
    spmm1_dual<<<nsb, dim3(24, 16), 0, stream>>>(
        (const float4*)y, row_start, csr_src, csr_perm, csr_norm, order, norm_out, norm_in,
        b1, a1, (float4*)h1s, (float4*)(h1s + (size_t)N * H96), N);

    gemm_kernel<<<(2 * N + BM - 1) / BM, 256, 0, stream>>>(h1s, W2, tbuf, 2 * N, H96);

    spmm2_dual<<<nsb, dim3(24, 16), 0, stream>>>(
        (const float4*)tbuf, row_start, csr_src, order, norm_in, b2, a2,
        wsum, bsum, out, N);
}